// Round 8
// baseline (541.164 us; speedup 1.0000x reference)
//
#include <hip/hip_runtime.h>
#include <math.h>
#include <stdint.h>

// Fused pipeline (E=300000, ND=100000, FEAT=256, RDIM=128):
//   prep:   weights -> bf16 fragment-ordered tables (lws additionally k-permuted)
//   CSR:    hist, scan, scan_bsum, add_offsets, build_eidx (sort edges by dst)
//   gather: rid_s/esrc_s = rid/esrc[eidx]
//   fused (512 thr = 8 waves (g=wid>>2 edge-group, f=wid&3 feat-quarter),
//          64 edges/block, 32KB LDS, launch_bounds(512,6) -> 3 blocks/CU):
//     s1 (swapped mfma, K=128): t1 = gelu(W1 @ remb_row) + pa/ra dots;
//         ga[i] = sigmoid(pa)*cj stored to global (segsum uses it); gvb kept in reg
//     s2 (swapped, K=256):      t2 = gelu(W2 @ t1)  (LDS in-place)
//     s3 (normal, K=256):       m = (t2 @ W3^T)*gvb ONLY (no feat here -> no big
//         reg array -> no spills), stored col-PERMUTED as packed b32:
//         stored[f*64 + l31*2 + n] = true col f*64 + n*32 + l31
//   segsum: h[d] = sum_i ( m[i] + ga[i]*feat[src_i] )   (feat added at permuted
//           positions; feat table is L3-resident)
//   g4:     out = (h @ lin_w^T)*ci + b   (perm inverted inside lws prep)
// mfma_f32_32x32x16_bf16 layouts (HW-validated R2-R7):
//   A: row=lane&31, k=8*(lane>>5)+j ; B: col=lane&31, same k
//   D: col=lane&31, row=(reg&3)+8*(reg>>2)+4*(lane>>5)
// LDS t: row=local edge (64), 512B/row, 16B-slot swizzle slot^=(row&7) (both sides).

typedef short bf16x8 __attribute__((ext_vector_type(8)));
typedef float f32x16 __attribute__((ext_vector_type(16)));

__device__ __forceinline__ float bf2f(unsigned short v) {
    union { unsigned int u; float f; } x; x.u = ((unsigned int)v) << 16; return x.f;
}
__device__ __forceinline__ unsigned short f2bf(float f) {
    union { float f; unsigned int u; } x; x.f = f;
    unsigned int u = x.u;
    return (unsigned short)((u + 0x7FFFu + ((u >> 16) & 1u)) >> 16);
}
__device__ __forceinline__ unsigned pack2(float lo, float hi) {
    return (unsigned)f2bf(lo) | ((unsigned)f2bf(hi) << 16);
}
__device__ __forceinline__ float gelu_erf(float x) {
    return 0.5f * x * (1.0f + erff(x * 0.70710678118654752f));
}
__device__ __forceinline__ float sigmoidf(float x) {
    return 1.0f / (1.0f + expf(-x));
}

// weights -> bf16 fragment-ordered tables; lws gets the m/h column perm baked in
__global__ __launch_bounds__(256) void prep_weights(
    const float* __restrict__ rw1, const float* __restrict__ rw2,
    const float* __restrict__ rw3, const float* __restrict__ lw,
    unsigned short* __restrict__ w1s, unsigned short* __restrict__ w2s,
    unsigned short* __restrict__ w3s, unsigned short* __restrict__ lws)
{
    int i = blockIdx.x * blockDim.x + threadIdx.x;
    int j   = i & 7;
    int l   = (i >> 3) & 31;
    int kgg = (i >> 8) & 1;
    int n2  = (i >> 9) & 7;
    int ks  = i >> 12;
    if (i < 32768) {   // K=128: ks 0..7
        w1s[i] = f2bf(rw1[(n2 * 32 + l) * 128 + ks * 16 + kgg * 8 + j]);
    }
    if (i < 65536) {   // K=256: ks 0..15
        int row = n2 * 32 + l, k = ks * 16 + kgg * 8 + j;
        w2s[i] = f2bf(rw2[(size_t)row * 256 + k]);
        w3s[i] = f2bf(rw3[(size_t)row * 256 + k]);
        // stored pos k holds true col: (k & ~63) + (k&1)*32 + ((k&63)>>1)
        int ok = (k & 192) | ((k & 1) << 5) | ((k & 63) >> 1);
        lws[i] = f2bf(lw[(size_t)row * 256 + ok]);
    }
}

// fragment load from pre-swizzled table (contiguous, coalesced)
__device__ __forceinline__ bf16x8 ldw(const unsigned short* __restrict__ W,
                                      int ks, int nglob, int kg, int l31) {
    return *(const bf16x8*)(W + (((((ks * 8 + nglob) * 2) + kg) * 32 + l31) << 3));
}

// ---------------- CSR build ----------------
__global__ __launch_bounds__(256) void hist_kernel(
    const int* __restrict__ edst, int* __restrict__ cnt,
    int* __restrict__ within, int E)
{
    int e = blockIdx.x * blockDim.x + threadIdx.x;
    if (e < E) within[e] = atomicAdd(&cnt[edst[e]], 1);
}

__global__ __launch_bounds__(1024) void scan_block(
    const int* __restrict__ cnt, int* __restrict__ start,
    int* __restrict__ bsum, int n)
{
    __shared__ int s[1024];
    int gid = blockIdx.x * 1024 + threadIdx.x;
    int v = (gid < n) ? cnt[gid] : 0;
    s[threadIdx.x] = v;
    __syncthreads();
    #pragma unroll
    for (int off = 1; off < 1024; off <<= 1) {
        int t = (threadIdx.x >= off) ? s[threadIdx.x - off] : 0;
        __syncthreads();
        if (threadIdx.x >= off) s[threadIdx.x] += t;
        __syncthreads();
    }
    if (gid < n) start[gid] = s[threadIdx.x] - v;   // exclusive
    if (threadIdx.x == 1023) bsum[blockIdx.x] = s[1023];
}

__global__ void scan_bsum(int* __restrict__ bsum, int nb) {
    if (threadIdx.x == 0 && blockIdx.x == 0) {
        int acc = 0;
        for (int i = 0; i < nb; ++i) { int v = bsum[i]; bsum[i] = acc; acc += v; }
    }
}

__global__ __launch_bounds__(1024) void add_offsets(
    int* __restrict__ start, const int* __restrict__ bsum, int n, int E)
{
    int gid = blockIdx.x * 1024 + threadIdx.x;
    if (gid < n) start[gid] += bsum[gid >> 10];
    if (gid == 0) start[n] = E;
}

__global__ __launch_bounds__(256) void build_eidx(
    const int* __restrict__ edst, const int* __restrict__ within,
    const int* __restrict__ start, int* __restrict__ eidx, int E)
{
    int e = blockIdx.x * blockDim.x + threadIdx.x;
    if (e < E) eidx[start[edst[e]] + within[e]] = e;
}

__global__ __launch_bounds__(256) void gather_sorted(
    const int* __restrict__ eidx, const int* __restrict__ rid,
    const int* __restrict__ esrc, int* __restrict__ rid_s,
    int* __restrict__ esrc_s, int E)
{
    int t = blockIdx.x * blockDim.x + threadIdx.x;
    if (t < E) { int e = eidx[t]; rid_s[t] = rid[e]; esrc_s[t] = esrc[e]; }
}

// ---------------- LDS t helpers (16B-slot XOR swizzle) ----------------
__device__ __forceinline__ bf16x8 ldtf(const unsigned short* t_lds, int row, int ks, int kg) {
    int slot = (ks * 2 + kg) ^ (row & 7);
    return *(const bf16x8*)((const char*)t_lds + row * 512 + slot * 16);
}
__device__ __forceinline__ void sttf(unsigned short* t_lds, int row, int nn, int p, int kg, uint2 w) {
    int slot = (nn * 4 + p) ^ (row & 7);
    *(uint2*)((char*)t_lds + row * 512 + slot * 16 + kg * 8) = w;
}

// ---------------- fused g1+g2+g3 ----------------
__global__ __launch_bounds__(512, 6) void fused_edge(
    const float* __restrict__ remb, const int* __restrict__ rid_s,
    const int* __restrict__ esrc_s,
    const unsigned short* __restrict__ w1s, const unsigned short* __restrict__ w2s,
    const unsigned short* __restrict__ w3s,
    const float* __restrict__ pw, const float* __restrict__ sw,
    const float* __restrict__ cj, float* __restrict__ ga,
    unsigned short* __restrict__ m, int E)
{
    __shared__ __align__(16) unsigned short t_lds[64 * 256];   // 32 KB

    const int lane = threadIdx.x & 63;
    const int wid  = threadIdx.x >> 6;       // 0..7
    const int l31  = lane & 31;
    const int kg   = lane >> 5;              // 0..1
    const int g    = wid >> 2;               // edge group (32 edges)
    const int f    = wid & 3;                // feature quarter (64 cols)
    const int blk0 = blockIdx.x * 64;
    const int i    = blk0 + g * 32 + l31;    // lane's edge
    const int ic   = (i < E) ? i : (E - 1);
    const int rid0 = rid_s[ic];
    const int src0 = esrc_s[ic];
    const int row_l = g * 32 + l31;          // local LDS row

    float gvb;

    // ================= stage 1: swapped, K=128, fused pa/ra =================
    {
        f32x16 acc[2];
        acc[0] = (f32x16)0.0f; acc[1] = (f32x16)0.0f;
        float pd = 0.f, rd = 0.f;
        const float* rbase = remb + (size_t)rid0 * 128;

        #pragma unroll
        for (int ks = 0; ks < 8; ++ks) {
            const int kk = ks * 16 + kg * 8;
            float4 u0 = *(const float4*)(rbase + kk);
            float4 u1 = *(const float4*)(rbase + kk + 4);
            float4 p0 = *(const float4*)(pw + kk), p1 = *(const float4*)(pw + kk + 4);
            float4 s0 = *(const float4*)(sw + kk), s1v = *(const float4*)(sw + kk + 4);
            pd += u0.x*p0.x + u0.y*p0.y + u0.z*p0.z + u0.w*p0.w
                + u1.x*p1.x + u1.y*p1.y + u1.z*p1.z + u1.w*p1.w;
            rd += u0.x*s0.x + u0.y*s0.y + u0.z*s0.z + u0.w*s0.w
                + u1.x*s1v.x + u1.y*s1v.y + u1.z*s1v.z + u1.w*s1v.w;
            union { unsigned u[4]; bf16x8 v; } bu;
            bu.u[0] = pack2(u0.x, u0.y); bu.u[1] = pack2(u0.z, u0.w);
            bu.u[2] = pack2(u1.x, u1.y); bu.u[3] = pack2(u1.z, u1.w);
            #pragma unroll
            for (int n = 0; n < 2; ++n) {
                bf16x8 wf = ldw(w1s, ks, f * 2 + n, kg, l31);
                acc[n] = __builtin_amdgcn_mfma_f32_32x32x16_bf16(wf, bu.v, acc[n], 0, 0, 0);
            }
        }

        pd += __shfl_xor(pd, 32);
        rd += __shfl_xor(rd, 32);
        float cjv = cj[src0];
        gvb = sigmoidf(rd) * cjv;
        if (f == 0 && lane < 32 && i < E) {
            ga[i] = sigmoidf(pd) * cjv;       // segsum applies feat[src]*ga
        }

        #pragma unroll
        for (int n = 0; n < 2; ++n)
            #pragma unroll
            for (int p = 0; p < 4; ++p) {
                uint2 w;
                w.x = pack2(gelu_erf(acc[n][4*p + 0]), gelu_erf(acc[n][4*p + 1]));
                w.y = pack2(gelu_erf(acc[n][4*p + 2]), gelu_erf(acc[n][4*p + 3]));
                sttf(t_lds, row_l, f * 2 + n, p, kg, w);
            }
    }
    __syncthreads();

    // ================= stage 2: swapped, K=256, LDS in-place =================
    {
        f32x16 acc[2];
        acc[0] = (f32x16)0.0f; acc[1] = (f32x16)0.0f;

        #pragma unroll
        for (int ks = 0; ks < 16; ++ks) {
            bf16x8 tf = ldtf(t_lds, row_l, ks, kg);
            #pragma unroll
            for (int n = 0; n < 2; ++n) {
                bf16x8 wf = ldw(w2s, ks, f * 2 + n, kg, l31);
                acc[n] = __builtin_amdgcn_mfma_f32_32x32x16_bf16(wf, tf, acc[n], 0, 0, 0);
            }
        }
        __syncthreads();   // all reads of t1 done before overwrite
        #pragma unroll
        for (int n = 0; n < 2; ++n)
            #pragma unroll
            for (int p = 0; p < 4; ++p) {
                uint2 w;
                w.x = pack2(gelu_erf(acc[n][4*p + 0]), gelu_erf(acc[n][4*p + 1]));
                w.y = pack2(gelu_erf(acc[n][4*p + 2]), gelu_erf(acc[n][4*p + 3]));
                sttf(t_lds, row_l, f * 2 + n, p, kg, w);
            }
    }
    __syncthreads();

    // ================= stage 3: normal, K=256, m = rf*gvb only =================
    {
        f32x16 acc[2];
        acc[0] = (f32x16)0.0f; acc[1] = (f32x16)0.0f;

        #pragma unroll
        for (int ks = 0; ks < 16; ++ks) {
            bf16x8 tf = ldtf(t_lds, row_l, ks, kg);
            #pragma unroll
            for (int n = 0; n < 2; ++n) {
                bf16x8 wf = ldw(w3s, ks, f * 2 + n, kg, l31);
                acc[n] = __builtin_amdgcn_mfma_f32_32x32x16_bf16(tf, wf, acc[n], 0, 0, 0);
            }
        }

        // epilogue: packed b32 stores, column-permuted within the f-quarter
        #pragma unroll
        for (int r = 0; r < 16; ++r) {
            const int lrow = (r & 3) + 8 * (r >> 2) + 4 * kg;
            const int gi = blk0 + g * 32 + lrow;
            if (gi < E) {
                float gbv = __shfl(gvb, g * 32 + lrow);
                float v0 = acc[0][r] * gbv;
                float v1 = acc[1][r] * gbv;
                *(unsigned*)(m + (size_t)gi * 256 + f * 64 + l31 * 2) = pack2(v0, v1);
            }
        }
    }
}

// ---------------- segment sum + feat gather: one wave per dst ----------------
// h[d] = sum_i ( m[i] + ga[i]*feat[src_i] ), all in the permuted column space:
// stored pos (q*64 + 4b + t), b=lane&15, maps to true col q*64 + {2b, 32+2b, 2b+1, 33+2b}
__global__ __launch_bounds__(256) void segsum_kernel(
    const int* __restrict__ start, const unsigned short* __restrict__ m,
    const float* __restrict__ ga, const int* __restrict__ esrc_s,
    const float* __restrict__ feat, unsigned short* __restrict__ h, int ND)
{
    int d = blockIdx.x * 4 + (threadIdx.x >> 6);
    if (d >= ND) return;
    int lane = threadIdx.x & 63;
    int q = lane >> 4;                 // feature quarter
    int b = lane & 15;
    int foff = q * 64 + 2 * b;         // true-col base for this lane
    int s0 = start[d], s1 = start[d + 1];
    float a0 = 0.f, a1 = 0.f, a2 = 0.f, a3 = 0.f;
    for (int i = s0; i < s1; ++i) {
        float gav = ga[i];
        const float* fp = feat + (size_t)esrc_s[i] * 256 + foff;
        float2 fa = *(const float2*)fp;          // true cols 2b, 2b+1
        float2 fb = *(const float2*)(fp + 32);   // true cols 32+2b, 33+2b
        ushort4 v = *(const ushort4*)(m + (size_t)i * 256 + lane * 4);
        a0 += bf2f(v.x) + fa.x * gav;
        a1 += bf2f(v.y) + fb.x * gav;
        a2 += bf2f(v.z) + fa.y * gav;
        a3 += bf2f(v.w) + fb.y * gav;
    }
    ushort4 o; o.x = f2bf(a0); o.y = f2bf(a1); o.z = f2bf(a2); o.w = f2bf(a3);
    *(ushort4*)(h + (size_t)d * 256 + lane * 4) = o;
}

// ---------------- g4: out = (h @ lin_w^T)*ci + b (perm baked into lws) ----------------
__global__ __launch_bounds__(256, 2) void g4_kernel(
    const unsigned short* __restrict__ Ab, const unsigned short* __restrict__ lws,
    float* __restrict__ outf, const float* __restrict__ ci,
    const float* __restrict__ bias, int M)
{
    const int lane = threadIdx.x & 63;
    const int wid  = threadIdx.x >> 6;
    const int l31  = lane & 31;
    const int kg   = lane >> 5;
    const int f    = wid & 1;                 // column half
    const int wbase = blockIdx.x * 128 + (wid >> 1) * 64;
    const int r0 = wbase + l31, r1 = wbase + 32 + l31;
    const int ar0 = (r0 < M) ? r0 : (M - 1);
    const int ar1 = (r1 < M) ? r1 : (M - 1);

    f32x16 acc[2][4];
    #pragma unroll
    for (int mi = 0; mi < 2; ++mi)
        #pragma unroll
        for (int n = 0; n < 4; ++n) acc[mi][n] = (f32x16)0.0f;

    #pragma unroll
    for (int ks = 0; ks < 16; ++ks) {
        const int kk = ks * 16 + kg * 8;
        bf16x8 a0 = *(const bf16x8*)(Ab + (size_t)ar0 * 256 + kk);
        bf16x8 a1 = *(const bf16x8*)(Ab + (size_t)ar1 * 256 + kk);
        #pragma unroll
        for (int n = 0; n < 4; ++n) {
            bf16x8 b = ldw(lws, ks, f * 4 + n, kg, l31);
            acc[0][n] = __builtin_amdgcn_mfma_f32_32x32x16_bf16(a0, b, acc[0][n], 0, 0, 0);
            acc[1][n] = __builtin_amdgcn_mfma_f32_32x32x16_bf16(a1, b, acc[1][n], 0, 0, 0);
        }
    }
    #pragma unroll
    for (int mi = 0; mi < 2; ++mi) {
        #pragma unroll
        for (int r = 0; r < 16; ++r) {
            const int gr = wbase + mi * 32 + (r & 3) + 8 * (r >> 2) + 4 * kg;
            if (gr >= M) continue;
            float civ = ci[gr];
            #pragma unroll
            for (int n = 0; n < 4; ++n) {
                int col = f * 128 + n * 32 + l31;
                outf[(size_t)gr * 256 + col] = acc[mi][n][r] * civ + bias[col];
            }
        }
    }
}

extern "C" void kernel_launch(void* const* d_in, const int* in_sizes, int n_in,
                              void* d_out, int out_size, void* d_ws, size_t ws_size,
                              hipStream_t stream) {
    const float* feat = (const float*)d_in[0];
    const float* cj   = (const float*)d_in[1];
    const float* ci   = (const float*)d_in[2];
    const int*   esrc = (const int*)d_in[3];
    const int*   edst = (const int*)d_in[4];
    const int*   rid  = (const int*)d_in[5];
    const float* remb = (const float*)d_in[6];
    const float* pw   = (const float*)d_in[7];
    const float* sw   = (const float*)d_in[8];
    const float* rw1  = (const float*)d_in[9];
    const float* rw2  = (const float*)d_in[10];
    const float* rw3  = (const float*)d_in[11];
    const float* lw   = (const float*)d_in[12];
    const float* lb   = (const float*)d_in[13];
    float* out = (float*)d_out;

    const int E  = in_sizes[3];   // 300000
    const int ND = in_sizes[2];   // 100000

    // workspace carve-up (~212 MB)
    char* ws = (char*)d_ws;
    float* ga = (float*)ws;                               // E f32
    unsigned short* m   = (unsigned short*)(ga + E);      // E*256 bf16 (permuted cols)
    unsigned short* h   = m + (size_t)E * 256;            // ND*256 bf16 (permuted cols)
    unsigned short* w1s = h + (size_t)ND * 256;           // 32768
    unsigned short* w2s = w1s + 32768;                    // 65536
    unsigned short* w3s = w2s + 65536;                    // 65536
    unsigned short* lws = w3s + 65536;                    // 65536
    int* cnt    = (int*)(lws + 65536);                    // ND
    int* start  = cnt + ND;                               // ND+1
    int* bsum   = start + ND + 1;                         // 128
    int* within = bsum + 128;                             // E
    int* eidx   = within + E;                             // E
    int* rid_s  = eidx + E;                               // E
    int* esrc_s = rid_s + E;                              // E

    const int NB = (ND + 1023) / 1024;

    hipMemsetAsync(cnt, 0, (size_t)ND * sizeof(int), stream);
    prep_weights<<<256, 256, 0, stream>>>(rw1, rw2, rw3, lw, w1s, w2s, w3s, lws);

    // CSR build + sorted-edge gathers
    hist_kernel<<<(E + 255) / 256, 256, 0, stream>>>(edst, cnt, within, E);
    scan_block<<<NB, 1024, 0, stream>>>(cnt, start, bsum, ND);
    scan_bsum<<<1, 64, 0, stream>>>(bsum, NB);
    add_offsets<<<NB, 1024, 0, stream>>>(start, bsum, ND, E);
    build_eidx<<<(E + 255) / 256, 256, 0, stream>>>(edst, within, start, eidx, E);
    gather_sorted<<<(E + 255) / 256, 256, 0, stream>>>(eidx, rid, esrc, rid_s, esrc_s, E);

    // fused g1+g2+g3 (8 waves, 64 edges/block, t staged in 32KB LDS, no feat)
    fused_edge<<<(E + 63) / 64, 512, 0, stream>>>(
        remb, rid_s, esrc_s, w1s, w2s, w3s, pw, sw, cj, ga, m, E);

    // segsum over contiguous sorted rows + feat[src]*ga gather
    segsum_kernel<<<(ND + 3) / 4, 256, 0, stream>>>(start, m, ga, esrc_s, feat, h, ND);

    // g4
    g4_kernel<<<(ND + 127) / 128, 256, 0, stream>>>(h, lws, out, ci, lb, ND);
}

// Round 9
// 478.878 us; speedup vs baseline: 1.1301x; 1.1301x over previous
//
#include <hip/hip_runtime.h>
#include <math.h>
#include <stdint.h>

// Fused pipeline (E=300000, ND=100000, FEAT=256, RDIM=128):
//   prep:   weights -> bf16 fragment-ordered tables (lws additionally k-permuted)
//   CSR:    hist, scan, scan_bsum, add_offsets, build_sorted (sort edges by dst,
//           directly emitting rid_s/esrc_s)
//   fused (512 thr = 8 waves (g=wid>>2 edge-group, f=wid&3 feat-quarter),
//          64 edges/block, 32KB LDS, launch_bounds(512,4): VGPR budget 128 ->
//          NO SPILLS (R6-R8 spilled ~260MB scratch at budgets 85/64)):
//     s1 (swapped mfma, K=128): t1 = gelu(W1 @ remb_row) + pa/ra dots;
//         ga[i] = sigmoid(pa)*cj -> global (segsum applies feat term); gvb in reg
//     s2 (swapped, K=256):      t2 = gelu(W2 @ t1)  (LDS in-place)
//     s3 (normal, K=256):       m = (t2 @ W3^T)*gvb, col-PERMUTED packed b32:
//         stored[f*64 + l31*2 + n] = true col f*64 + n*32 + l31
//   segsum: h[d] = sum_i ( m[i] + ga[i]*feat[src_i] )  (permuted space)
//   g4:     out = (h @ lin_w^T)*ci + b   (perm inverted inside lws prep)
// mfma_f32_32x32x16_bf16 layouts (HW-validated R2-R8):
//   A: row=lane&31, k=8*(lane>>5)+j ; B: col=lane&31, same k
//   D: col=lane&31, row=(reg&3)+8*(reg>>2)+4*(lane>>5)
// LDS t: row=local edge (64), 512B/row, 16B-slot swizzle slot^=(row&7) (both sides).

typedef short bf16x8 __attribute__((ext_vector_type(8)));
typedef float f32x16 __attribute__((ext_vector_type(16)));

__device__ __forceinline__ float bf2f(unsigned short v) {
    union { unsigned int u; float f; } x; x.u = ((unsigned int)v) << 16; return x.f;
}
__device__ __forceinline__ unsigned short f2bf(float f) {
    union { float f; unsigned int u; } x; x.f = f;
    unsigned int u = x.u;
    return (unsigned short)((u + 0x7FFFu + ((u >> 16) & 1u)) >> 16);
}
__device__ __forceinline__ unsigned pack2(float lo, float hi) {
    return (unsigned)f2bf(lo) | ((unsigned)f2bf(hi) << 16);
}
__device__ __forceinline__ float gelu_erf(float x) {
    return 0.5f * x * (1.0f + erff(x * 0.70710678118654752f));
}
__device__ __forceinline__ float sigmoidf(float x) {
    return 1.0f / (1.0f + expf(-x));
}

// weights -> bf16 fragment-ordered tables; lws gets the m/h column perm baked in
__global__ __launch_bounds__(256) void prep_weights(
    const float* __restrict__ rw1, const float* __restrict__ rw2,
    const float* __restrict__ rw3, const float* __restrict__ lw,
    unsigned short* __restrict__ w1s, unsigned short* __restrict__ w2s,
    unsigned short* __restrict__ w3s, unsigned short* __restrict__ lws)
{
    int i = blockIdx.x * blockDim.x + threadIdx.x;
    int j   = i & 7;
    int l   = (i >> 3) & 31;
    int kgg = (i >> 8) & 1;
    int n2  = (i >> 9) & 7;
    int ks  = i >> 12;
    if (i < 32768) {   // K=128: ks 0..7
        w1s[i] = f2bf(rw1[(n2 * 32 + l) * 128 + ks * 16 + kgg * 8 + j]);
    }
    if (i < 65536) {   // K=256: ks 0..15
        int row = n2 * 32 + l, k = ks * 16 + kgg * 8 + j;
        w2s[i] = f2bf(rw2[(size_t)row * 256 + k]);
        w3s[i] = f2bf(rw3[(size_t)row * 256 + k]);
        // stored pos k holds true col: (k & ~63) + (k&1)*32 + ((k&63)>>1)
        int ok = (k & 192) | ((k & 1) << 5) | ((k & 63) >> 1);
        lws[i] = f2bf(lw[(size_t)row * 256 + ok]);
    }
}

// fragment load from pre-swizzled table (contiguous, coalesced)
__device__ __forceinline__ bf16x8 ldw(const unsigned short* __restrict__ W,
                                      int ks, int nglob, int kg, int l31) {
    return *(const bf16x8*)(W + (((((ks * 8 + nglob) * 2) + kg) * 32 + l31) << 3));
}

// ---------------- CSR build ----------------
__global__ __launch_bounds__(256) void hist_kernel(
    const int* __restrict__ edst, int* __restrict__ cnt,
    int* __restrict__ within, int E)
{
    int e = blockIdx.x * blockDim.x + threadIdx.x;
    if (e < E) within[e] = atomicAdd(&cnt[edst[e]], 1);
}

__global__ __launch_bounds__(1024) void scan_block(
    const int* __restrict__ cnt, int* __restrict__ start,
    int* __restrict__ bsum, int n)
{
    __shared__ int s[1024];
    int gid = blockIdx.x * 1024 + threadIdx.x;
    int v = (gid < n) ? cnt[gid] : 0;
    s[threadIdx.x] = v;
    __syncthreads();
    #pragma unroll
    for (int off = 1; off < 1024; off <<= 1) {
        int t = (threadIdx.x >= off) ? s[threadIdx.x - off] : 0;
        __syncthreads();
        if (threadIdx.x >= off) s[threadIdx.x] += t;
        __syncthreads();
    }
    if (gid < n) start[gid] = s[threadIdx.x] - v;   // exclusive
    if (threadIdx.x == 1023) bsum[blockIdx.x] = s[1023];
}

__global__ void scan_bsum(int* __restrict__ bsum, int nb) {
    if (threadIdx.x == 0 && blockIdx.x == 0) {
        int acc = 0;
        for (int i = 0; i < nb; ++i) { int v = bsum[i]; bsum[i] = acc; acc += v; }
    }
}

__global__ __launch_bounds__(1024) void add_offsets(
    int* __restrict__ start, const int* __restrict__ bsum, int n, int E)
{
    int gid = blockIdx.x * 1024 + threadIdx.x;
    if (gid < n) start[gid] += bsum[gid >> 10];
    if (gid == 0) start[n] = E;
}

// counting sort: directly emit dst-sorted rid/esrc (no eidx indirection)
__global__ __launch_bounds__(256) void build_sorted(
    const int* __restrict__ edst, const int* __restrict__ within,
    const int* __restrict__ start, const int* __restrict__ rid,
    const int* __restrict__ esrc, int* __restrict__ rid_s,
    int* __restrict__ esrc_s, int E)
{
    int e = blockIdx.x * blockDim.x + threadIdx.x;
    if (e < E) {
        int pos = start[edst[e]] + within[e];
        rid_s[pos]  = rid[e];
        esrc_s[pos] = esrc[e];
    }
}

// ---------------- LDS t helpers (16B-slot XOR swizzle) ----------------
__device__ __forceinline__ bf16x8 ldtf(const unsigned short* t_lds, int row, int ks, int kg) {
    int slot = (ks * 2 + kg) ^ (row & 7);
    return *(const bf16x8*)((const char*)t_lds + row * 512 + slot * 16);
}
__device__ __forceinline__ void sttf(unsigned short* t_lds, int row, int nn, int p, int kg, uint2 w) {
    int slot = (nn * 4 + p) ^ (row & 7);
    *(uint2*)((char*)t_lds + row * 512 + slot * 16 + kg * 8) = w;
}

// ---------------- fused g1+g2+g3 ----------------
__global__ __launch_bounds__(512, 4) void fused_edge(
    const float* __restrict__ remb, const int* __restrict__ rid_s,
    const int* __restrict__ esrc_s,
    const unsigned short* __restrict__ w1s, const unsigned short* __restrict__ w2s,
    const unsigned short* __restrict__ w3s,
    const float* __restrict__ pw, const float* __restrict__ sw,
    const float* __restrict__ cj, float* __restrict__ ga,
    unsigned short* __restrict__ m, int E)
{
    __shared__ __align__(16) unsigned short t_lds[64 * 256];   // 32 KB

    const int lane = threadIdx.x & 63;
    const int wid  = threadIdx.x >> 6;       // 0..7
    const int l31  = lane & 31;
    const int kg   = lane >> 5;              // 0..1
    const int g    = wid >> 2;               // edge group (32 edges)
    const int f    = wid & 3;                // feature quarter (64 cols)
    const int blk0 = blockIdx.x * 64;
    const int i    = blk0 + g * 32 + l31;    // lane's edge
    const int ic   = (i < E) ? i : (E - 1);
    const int rid0 = rid_s[ic];
    const int src0 = esrc_s[ic];
    const int row_l = g * 32 + l31;          // local LDS row

    float gvb;

    // ================= stage 1: swapped, K=128, fused pa/ra =================
    {
        f32x16 acc[2];
        acc[0] = (f32x16)0.0f; acc[1] = (f32x16)0.0f;
        float pd = 0.f, rd = 0.f;
        const float* rbase = remb + (size_t)rid0 * 128;

        #pragma unroll
        for (int ks = 0; ks < 8; ++ks) {
            const int kk = ks * 16 + kg * 8;
            float4 u0 = *(const float4*)(rbase + kk);
            float4 u1 = *(const float4*)(rbase + kk + 4);
            float4 p0 = *(const float4*)(pw + kk), p1 = *(const float4*)(pw + kk + 4);
            float4 s0 = *(const float4*)(sw + kk), s1v = *(const float4*)(sw + kk + 4);
            pd += u0.x*p0.x + u0.y*p0.y + u0.z*p0.z + u0.w*p0.w
                + u1.x*p1.x + u1.y*p1.y + u1.z*p1.z + u1.w*p1.w;
            rd += u0.x*s0.x + u0.y*s0.y + u0.z*s0.z + u0.w*s0.w
                + u1.x*s1v.x + u1.y*s1v.y + u1.z*s1v.z + u1.w*s1v.w;
            union { unsigned u[4]; bf16x8 v; } bu;
            bu.u[0] = pack2(u0.x, u0.y); bu.u[1] = pack2(u0.z, u0.w);
            bu.u[2] = pack2(u1.x, u1.y); bu.u[3] = pack2(u1.z, u1.w);
            #pragma unroll
            for (int n = 0; n < 2; ++n) {
                bf16x8 wf = ldw(w1s, ks, f * 2 + n, kg, l31);
                acc[n] = __builtin_amdgcn_mfma_f32_32x32x16_bf16(wf, bu.v, acc[n], 0, 0, 0);
            }
        }

        pd += __shfl_xor(pd, 32);
        rd += __shfl_xor(rd, 32);
        float cjv = cj[src0];
        gvb = sigmoidf(rd) * cjv;
        if (f == 0 && lane < 32 && i < E) {
            ga[i] = sigmoidf(pd) * cjv;       // segsum applies feat[src]*ga
        }

        #pragma unroll
        for (int n = 0; n < 2; ++n)
            #pragma unroll
            for (int p = 0; p < 4; ++p) {
                uint2 w;
                w.x = pack2(gelu_erf(acc[n][4*p + 0]), gelu_erf(acc[n][4*p + 1]));
                w.y = pack2(gelu_erf(acc[n][4*p + 2]), gelu_erf(acc[n][4*p + 3]));
                sttf(t_lds, row_l, f * 2 + n, p, kg, w);
            }
    }
    __syncthreads();

    // ================= stage 2: swapped, K=256, LDS in-place =================
    {
        f32x16 acc[2];
        acc[0] = (f32x16)0.0f; acc[1] = (f32x16)0.0f;

        #pragma unroll
        for (int ks = 0; ks < 16; ++ks) {
            bf16x8 tf = ldtf(t_lds, row_l, ks, kg);
            #pragma unroll
            for (int n = 0; n < 2; ++n) {
                bf16x8 wf = ldw(w2s, ks, f * 2 + n, kg, l31);
                acc[n] = __builtin_amdgcn_mfma_f32_32x32x16_bf16(wf, tf, acc[n], 0, 0, 0);
            }
        }
        __syncthreads();   // all reads of t1 done before overwrite
        #pragma unroll
        for (int n = 0; n < 2; ++n)
            #pragma unroll
            for (int p = 0; p < 4; ++p) {
                uint2 w;
                w.x = pack2(gelu_erf(acc[n][4*p + 0]), gelu_erf(acc[n][4*p + 1]));
                w.y = pack2(gelu_erf(acc[n][4*p + 2]), gelu_erf(acc[n][4*p + 3]));
                sttf(t_lds, row_l, f * 2 + n, p, kg, w);
            }
    }
    __syncthreads();

    // ================= stage 3: normal, K=256, m = rf*gvb only =================
    {
        f32x16 acc[2];
        acc[0] = (f32x16)0.0f; acc[1] = (f32x16)0.0f;

        #pragma unroll
        for (int ks = 0; ks < 16; ++ks) {
            bf16x8 tf = ldtf(t_lds, row_l, ks, kg);
            #pragma unroll
            for (int n = 0; n < 2; ++n) {
                bf16x8 wf = ldw(w3s, ks, f * 2 + n, kg, l31);
                acc[n] = __builtin_amdgcn_mfma_f32_32x32x16_bf16(tf, wf, acc[n], 0, 0, 0);
            }
        }

        // epilogue: packed b32 stores, column-permuted within the f-quarter
        #pragma unroll
        for (int r = 0; r < 16; ++r) {
            const int lrow = (r & 3) + 8 * (r >> 2) + 4 * kg;
            const int gi = blk0 + g * 32 + lrow;
            if (gi < E) {
                float gbv = __shfl(gvb, g * 32 + lrow);
                float v0 = acc[0][r] * gbv;
                float v1 = acc[1][r] * gbv;
                *(unsigned*)(m + (size_t)gi * 256 + f * 64 + l31 * 2) = pack2(v0, v1);
            }
        }
    }
}

// ---------------- segment sum + feat gather: one wave per dst ----------------
// h[d] = sum_i ( m[i] + ga[i]*feat[src_i] ), all in the permuted column space:
// stored pos (q*64 + 4b + t), b=lane&15, maps to true col q*64 + {2b, 32+2b, 2b+1, 33+2b}
__global__ __launch_bounds__(256) void segsum_kernel(
    const int* __restrict__ start, const unsigned short* __restrict__ m,
    const float* __restrict__ ga, const int* __restrict__ esrc_s,
    const float* __restrict__ feat, unsigned short* __restrict__ h, int ND)
{
    int d = blockIdx.x * 4 + (threadIdx.x >> 6);
    if (d >= ND) return;
    int lane = threadIdx.x & 63;
    int q = lane >> 4;                 // feature quarter
    int b = lane & 15;
    int foff = q * 64 + 2 * b;         // true-col base for this lane
    int s0 = start[d], s1 = start[d + 1];
    float a0 = 0.f, a1 = 0.f, a2 = 0.f, a3 = 0.f;
    for (int i = s0; i < s1; ++i) {
        float gav = ga[i];
        const float* fp = feat + (size_t)esrc_s[i] * 256 + foff;
        float2 fa = *(const float2*)fp;          // true cols 2b, 2b+1
        float2 fb = *(const float2*)(fp + 32);   // true cols 32+2b, 33+2b
        ushort4 v = *(const ushort4*)(m + (size_t)i * 256 + lane * 4);
        a0 += bf2f(v.x) + fa.x * gav;
        a1 += bf2f(v.y) + fb.x * gav;
        a2 += bf2f(v.z) + fa.y * gav;
        a3 += bf2f(v.w) + fb.y * gav;
    }
    ushort4 o; o.x = f2bf(a0); o.y = f2bf(a1); o.z = f2bf(a2); o.w = f2bf(a3);
    *(ushort4*)(h + (size_t)d * 256 + lane * 4) = o;
}

// ---------------- g4: out = (h @ lin_w^T)*ci + b (perm baked into lws) ----------------
__global__ __launch_bounds__(256, 2) void g4_kernel(
    const unsigned short* __restrict__ Ab, const unsigned short* __restrict__ lws,
    float* __restrict__ outf, const float* __restrict__ ci,
    const float* __restrict__ bias, int M)
{
    const int lane = threadIdx.x & 63;
    const int wid  = threadIdx.x >> 6;
    const int l31  = lane & 31;
    const int kg   = lane >> 5;
    const int f    = wid & 1;                 // column half
    const int wbase = blockIdx.x * 128 + (wid >> 1) * 64;
    const int r0 = wbase + l31, r1 = wbase + 32 + l31;
    const int ar0 = (r0 < M) ? r0 : (M - 1);
    const int ar1 = (r1 < M) ? r1 : (M - 1);

    f32x16 acc[2][4];
    #pragma unroll
    for (int mi = 0; mi < 2; ++mi)
        #pragma unroll
        for (int n = 0; n < 4; ++n) acc[mi][n] = (f32x16)0.0f;

    #pragma unroll
    for (int ks = 0; ks < 16; ++ks) {
        const int kk = ks * 16 + kg * 8;
        bf16x8 a0 = *(const bf16x8*)(Ab + (size_t)ar0 * 256 + kk);
        bf16x8 a1 = *(const bf16x8*)(Ab + (size_t)ar1 * 256 + kk);
        #pragma unroll
        for (int n = 0; n < 4; ++n) {
            bf16x8 b = ldw(lws, ks, f * 4 + n, kg, l31);
            acc[0][n] = __builtin_amdgcn_mfma_f32_32x32x16_bf16(a0, b, acc[0][n], 0, 0, 0);
            acc[1][n] = __builtin_amdgcn_mfma_f32_32x32x16_bf16(a1, b, acc[1][n], 0, 0, 0);
        }
    }
    #pragma unroll
    for (int mi = 0; mi < 2; ++mi) {
        #pragma unroll
        for (int r = 0; r < 16; ++r) {
            const int gr = wbase + mi * 32 + (r & 3) + 8 * (r >> 2) + 4 * kg;
            if (gr >= M) continue;
            float civ = ci[gr];
            #pragma unroll
            for (int n = 0; n < 4; ++n) {
                int col = f * 128 + n * 32 + l31;
                outf[(size_t)gr * 256 + col] = acc[mi][n][r] * civ + bias[col];
            }
        }
    }
}

extern "C" void kernel_launch(void* const* d_in, const int* in_sizes, int n_in,
                              void* d_out, int out_size, void* d_ws, size_t ws_size,
                              hipStream_t stream) {
    const float* feat = (const float*)d_in[0];
    const float* cj   = (const float*)d_in[1];
    const float* ci   = (const float*)d_in[2];
    const int*   esrc = (const int*)d_in[3];
    const int*   edst = (const int*)d_in[4];
    const int*   rid  = (const int*)d_in[5];
    const float* remb = (const float*)d_in[6];
    const float* pw   = (const float*)d_in[7];
    const float* sw   = (const float*)d_in[8];
    const float* rw1  = (const float*)d_in[9];
    const float* rw2  = (const float*)d_in[10];
    const float* rw3  = (const float*)d_in[11];
    const float* lw   = (const float*)d_in[12];
    const float* lb   = (const float*)d_in[13];
    float* out = (float*)d_out;

    const int E  = in_sizes[3];   // 300000
    const int ND = in_sizes[2];   // 100000

    // workspace carve-up (~210 MB)
    char* ws = (char*)d_ws;
    float* ga = (float*)ws;                               // E f32
    unsigned short* m   = (unsigned short*)(ga + E);      // E*256 bf16 (permuted cols)
    unsigned short* h   = m + (size_t)E * 256;            // ND*256 bf16 (permuted cols)
    unsigned short* w1s = h + (size_t)ND * 256;           // 32768
    unsigned short* w2s = w1s + 32768;                    // 65536
    unsigned short* w3s = w2s + 65536;                    // 65536
    unsigned short* lws = w3s + 65536;                    // 65536
    int* cnt    = (int*)(lws + 65536);                    // ND
    int* start  = cnt + ND;                               // ND+1
    int* bsum   = start + ND + 1;                         // 128
    int* within = bsum + 128;                             // E
    int* rid_s  = within + E;                             // E
    int* esrc_s = rid_s + E;                              // E

    const int NB = (ND + 1023) / 1024;

    hipMemsetAsync(cnt, 0, (size_t)ND * sizeof(int), stream);
    prep_weights<<<256, 256, 0, stream>>>(rw1, rw2, rw3, lw, w1s, w2s, w3s, lws);

    // CSR build + direct sorted-edge emit
    hist_kernel<<<(E + 255) / 256, 256, 0, stream>>>(edst, cnt, within, E);
    scan_block<<<NB, 1024, 0, stream>>>(cnt, start, bsum, ND);
    scan_bsum<<<1, 64, 0, stream>>>(bsum, NB);
    add_offsets<<<NB, 1024, 0, stream>>>(start, bsum, ND, E);
    build_sorted<<<(E + 255) / 256, 256, 0, stream>>>(edst, within, start, rid, esrc,
                                                      rid_s, esrc_s, E);

    // fused g1+g2+g3 (8 waves, 64 edges/block, t staged in 32KB LDS, no spills)
    fused_edge<<<(E + 63) / 64, 512, 0, stream>>>(
        remb, rid_s, esrc_s, w1s, w2s, w3s, pw, sw, cj, ga, m, E);

    // segsum over contiguous sorted rows + feat[src]*ga gather
    segsum_kernel<<<(ND + 3) / 4, 256, 0, stream>>>(start, m, ga, esrc_s, feat, h, ND);

    // g4
    g4_kernel<<<(ND + 127) / 128, 256, 0, stream>>>(h, lws, out, ci, lb, ND);
}

// Round 10
// 464.306 us; speedup vs baseline: 1.1655x; 1.0314x over previous
//
#include <hip/hip_runtime.h>
#include <math.h>
#include <stdint.h>

// Fused pipeline (E=300000, ND=100000, FEAT=256, RDIM=128):
//   prep:   weights -> bf16 fragment-ordered tables (lws additionally k-permuted)
//   CSR:    hist, scan, scan_bsum, add_offsets, build_sorted (dst-sorted rid_s/esrc_s)
//   fused (256 thr = 4 waves, one per feature-quarter f; 32 edges/block; 16KB LDS;
//          launch_bounds(256,5) -> 5 blocks/CU = 20 waves/CU):
//     s1 (swapped mfma, K=128): t1 = gelu(W1 @ remb_row); pa/ra dots ONLY in f==0
//         wave -> ga[i] global, gvb -> gvb_lds[32] (others read it in s3)
//     s2 (swapped, K=256):      t2 = gelu(W2 @ t1)  (LDS in-place)
//     s3 (normal, K=256):       m = (t2 @ W3^T)*gvb, col-PERMUTED packed b32:
//         stored[f*64 + l31*2 + n] = true col f*64 + n*32 + l31
//   segsum: h[d] = sum_i ( m[i] + ga[i]*feat[src_i] )  (permuted space)
//   g4:     out = (h @ lin_w^T)*ci + b   (perm inverted inside lws prep)
// VALU diet (R10): v_cvt_pk_bf16_f32 single-instr packs; tanh-approx gelu
// (|err| ~1e-3 intermediate, negligible after 0.03-scale weight dots).
// mfma_f32_32x32x16_bf16 layouts (HW-validated R2-R9):
//   A: row=lane&31, k=8*(lane>>5)+j ; B: col=lane&31, same k
//   D: col=lane&31, row=(reg&3)+8*(reg>>2)+4*(lane>>5)
// LDS t: row=local edge (32), 512B/row, 16B-slot swizzle slot^=(row&7) (both sides).

typedef short bf16x8 __attribute__((ext_vector_type(8)));
typedef float f32x16 __attribute__((ext_vector_type(16)));

__device__ __forceinline__ float bf2f(unsigned short v) {
    union { unsigned int u; float f; } x; x.u = ((unsigned int)v) << 16; return x.f;
}
__device__ __forceinline__ unsigned short f2bf(float f) {
    union { float f; unsigned int u; } x; x.f = f;
    unsigned int u = x.u;
    return (unsigned short)((u + 0x7FFFu + ((u >> 16) & 1u)) >> 16);
}
// single-instruction packed f32x2 -> bf16x2 (RTNE), low16 = lo
__device__ __forceinline__ unsigned pack2(float lo, float hi) {
    unsigned r;
    asm("v_cvt_pk_bf16_f32 %0, %1, %2" : "=v"(r) : "v"(lo), "v"(hi));
    return r;
}
// tanh-approx GELU: 0.5x(1+tanh(0.79788456(x+0.044715x^3)));  ~8 VALU ops
__device__ __forceinline__ float gelu_fast(float x) {
    float y = x * (0.7978845608f + 0.0356774081f * x * x);
    float e = __builtin_amdgcn_exp2f(y * 2.8853900818f);   // e^(2y)
    float th = 1.0f - 2.0f * __builtin_amdgcn_rcpf(e + 1.0f);
    return 0.5f * x * (1.0f + th);
}
__device__ __forceinline__ float sigmoidf(float x) {
    return 1.0f / (1.0f + expf(-x));
}

// weights -> bf16 fragment-ordered tables; lws gets the m/h column perm baked in
__global__ __launch_bounds__(256) void prep_weights(
    const float* __restrict__ rw1, const float* __restrict__ rw2,
    const float* __restrict__ rw3, const float* __restrict__ lw,
    unsigned short* __restrict__ w1s, unsigned short* __restrict__ w2s,
    unsigned short* __restrict__ w3s, unsigned short* __restrict__ lws)
{
    int i = blockIdx.x * blockDim.x + threadIdx.x;
    int j   = i & 7;
    int l   = (i >> 3) & 31;
    int kgg = (i >> 8) & 1;
    int n2  = (i >> 9) & 7;
    int ks  = i >> 12;
    if (i < 32768) {   // K=128: ks 0..7
        w1s[i] = f2bf(rw1[(n2 * 32 + l) * 128 + ks * 16 + kgg * 8 + j]);
    }
    if (i < 65536) {   // K=256: ks 0..15
        int row = n2 * 32 + l, k = ks * 16 + kgg * 8 + j;
        w2s[i] = f2bf(rw2[(size_t)row * 256 + k]);
        w3s[i] = f2bf(rw3[(size_t)row * 256 + k]);
        // stored pos k holds true col: (k & ~63) + (k&1)*32 + ((k&63)>>1)
        int ok = (k & 192) | ((k & 1) << 5) | ((k & 63) >> 1);
        lws[i] = f2bf(lw[(size_t)row * 256 + ok]);
    }
}

// fragment load from pre-swizzled table (contiguous, coalesced)
__device__ __forceinline__ bf16x8 ldw(const unsigned short* __restrict__ W,
                                      int ks, int nglob, int kg, int l31) {
    return *(const bf16x8*)(W + (((((ks * 8 + nglob) * 2) + kg) * 32 + l31) << 3));
}

// ---------------- CSR build ----------------
__global__ __launch_bounds__(256) void hist_kernel(
    const int* __restrict__ edst, int* __restrict__ cnt,
    int* __restrict__ within, int E)
{
    int e = blockIdx.x * blockDim.x + threadIdx.x;
    if (e < E) within[e] = atomicAdd(&cnt[edst[e]], 1);
}

__global__ __launch_bounds__(1024) void scan_block(
    const int* __restrict__ cnt, int* __restrict__ start,
    int* __restrict__ bsum, int n)
{
    __shared__ int s[1024];
    int gid = blockIdx.x * 1024 + threadIdx.x;
    int v = (gid < n) ? cnt[gid] : 0;
    s[threadIdx.x] = v;
    __syncthreads();
    #pragma unroll
    for (int off = 1; off < 1024; off <<= 1) {
        int t = (threadIdx.x >= off) ? s[threadIdx.x - off] : 0;
        __syncthreads();
        if (threadIdx.x >= off) s[threadIdx.x] += t;
        __syncthreads();
    }
    if (gid < n) start[gid] = s[threadIdx.x] - v;   // exclusive
    if (threadIdx.x == 1023) bsum[blockIdx.x] = s[1023];
}

__global__ void scan_bsum(int* __restrict__ bsum, int nb) {
    if (threadIdx.x == 0 && blockIdx.x == 0) {
        int acc = 0;
        for (int i = 0; i < nb; ++i) { int v = bsum[i]; bsum[i] = acc; acc += v; }
    }
}

__global__ __launch_bounds__(1024) void add_offsets(
    int* __restrict__ start, const int* __restrict__ bsum, int n, int E)
{
    int gid = blockIdx.x * 1024 + threadIdx.x;
    if (gid < n) start[gid] += bsum[gid >> 10];
    if (gid == 0) start[n] = E;
}

// counting sort: directly emit dst-sorted rid/esrc (no eidx indirection)
__global__ __launch_bounds__(256) void build_sorted(
    const int* __restrict__ edst, const int* __restrict__ within,
    const int* __restrict__ start, const int* __restrict__ rid,
    const int* __restrict__ esrc, int* __restrict__ rid_s,
    int* __restrict__ esrc_s, int E)
{
    int e = blockIdx.x * blockDim.x + threadIdx.x;
    if (e < E) {
        int pos = start[edst[e]] + within[e];
        rid_s[pos]  = rid[e];
        esrc_s[pos] = esrc[e];
    }
}

// ---------------- LDS t helpers (16B-slot XOR swizzle) ----------------
__device__ __forceinline__ bf16x8 ldtf(const unsigned short* t_lds, int row, int ks, int kg) {
    int slot = (ks * 2 + kg) ^ (row & 7);
    return *(const bf16x8*)((const char*)t_lds + row * 512 + slot * 16);
}
__device__ __forceinline__ void sttf(unsigned short* t_lds, int row, int nn, int p, int kg, uint2 w) {
    int slot = (nn * 4 + p) ^ (row & 7);
    *(uint2*)((char*)t_lds + row * 512 + slot * 16 + kg * 8) = w;
}

// ---------------- fused g1+g2+g3 ----------------
__global__ __launch_bounds__(256, 5) void fused_edge(
    const float* __restrict__ remb, const int* __restrict__ rid_s,
    const int* __restrict__ esrc_s,
    const unsigned short* __restrict__ w1s, const unsigned short* __restrict__ w2s,
    const unsigned short* __restrict__ w3s,
    const float* __restrict__ pw, const float* __restrict__ sw,
    const float* __restrict__ cj, float* __restrict__ ga,
    unsigned short* __restrict__ m, int E)
{
    __shared__ __align__(16) unsigned short t_lds[32 * 256];   // 16 KB
    __shared__ float gvb_lds[32];

    const int lane = threadIdx.x & 63;
    const int f    = threadIdx.x >> 6;       // wave = feature quarter 0..3
    const int l31  = lane & 31;
    const int kg   = lane >> 5;              // 0..1
    const int blk0 = blockIdx.x * 32;
    const int i    = blk0 + l31;             // lane's edge
    const int ic   = (i < E) ? i : (E - 1);
    const int rid0 = rid_s[ic];
    const int row_l = l31;                   // local LDS row

    // ================= stage 1: swapped, K=128 (+ dots in f==0) =================
    {
        f32x16 acc[2];
        acc[0] = (f32x16)0.0f; acc[1] = (f32x16)0.0f;
        float pd = 0.f, rd = 0.f;
        const float* rbase = remb + (size_t)rid0 * 128;

        #pragma unroll
        for (int ks = 0; ks < 8; ++ks) {
            const int kk = ks * 16 + kg * 8;
            float4 u0 = *(const float4*)(rbase + kk);
            float4 u1 = *(const float4*)(rbase + kk + 4);
            if (f == 0) {   // wave-uniform branch: only f==0 pays for the dots
                float4 p0 = *(const float4*)(pw + kk), p1 = *(const float4*)(pw + kk + 4);
                float4 s0 = *(const float4*)(sw + kk), s1v = *(const float4*)(sw + kk + 4);
                pd += u0.x*p0.x + u0.y*p0.y + u0.z*p0.z + u0.w*p0.w
                    + u1.x*p1.x + u1.y*p1.y + u1.z*p1.z + u1.w*p1.w;
                rd += u0.x*s0.x + u0.y*s0.y + u0.z*s0.z + u0.w*s0.w
                    + u1.x*s1v.x + u1.y*s1v.y + u1.z*s1v.z + u1.w*s1v.w;
            }
            union { unsigned u[4]; bf16x8 v; } bu;
            bu.u[0] = pack2(u0.x, u0.y); bu.u[1] = pack2(u0.z, u0.w);
            bu.u[2] = pack2(u1.x, u1.y); bu.u[3] = pack2(u1.z, u1.w);
            #pragma unroll
            for (int n = 0; n < 2; ++n) {
                bf16x8 wf = ldw(w1s, ks, f * 2 + n, kg, l31);
                acc[n] = __builtin_amdgcn_mfma_f32_32x32x16_bf16(wf, bu.v, acc[n], 0, 0, 0);
            }
        }

        if (f == 0) {
            pd += __shfl_xor(pd, 32);
            rd += __shfl_xor(rd, 32);
            if (lane < 32) {
                float cjv = cj[esrc_s[ic]];
                if (i < E) ga[i] = sigmoidf(pd) * cjv;   // segsum applies feat term
                gvb_lds[l31] = sigmoidf(rd) * cjv;
            }
        }

        #pragma unroll
        for (int n = 0; n < 2; ++n)
            #pragma unroll
            for (int p = 0; p < 4; ++p) {
                uint2 w;
                w.x = pack2(gelu_fast(acc[n][4*p + 0]), gelu_fast(acc[n][4*p + 1]));
                w.y = pack2(gelu_fast(acc[n][4*p + 2]), gelu_fast(acc[n][4*p + 3]));
                sttf(t_lds, row_l, f * 2 + n, p, kg, w);
            }
    }
    __syncthreads();

    // ================= stage 2: swapped, K=256, LDS in-place =================
    {
        f32x16 acc[2];
        acc[0] = (f32x16)0.0f; acc[1] = (f32x16)0.0f;

        #pragma unroll
        for (int ks = 0; ks < 16; ++ks) {
            bf16x8 tf = ldtf(t_lds, row_l, ks, kg);
            #pragma unroll
            for (int n = 0; n < 2; ++n) {
                bf16x8 wf = ldw(w2s, ks, f * 2 + n, kg, l31);
                acc[n] = __builtin_amdgcn_mfma_f32_32x32x16_bf16(wf, tf, acc[n], 0, 0, 0);
            }
        }
        __syncthreads();   // all reads of t1 done before overwrite
        #pragma unroll
        for (int n = 0; n < 2; ++n)
            #pragma unroll
            for (int p = 0; p < 4; ++p) {
                uint2 w;
                w.x = pack2(gelu_fast(acc[n][4*p + 0]), gelu_fast(acc[n][4*p + 1]));
                w.y = pack2(gelu_fast(acc[n][4*p + 2]), gelu_fast(acc[n][4*p + 3]));
                sttf(t_lds, row_l, f * 2 + n, p, kg, w);
            }
    }
    __syncthreads();

    // ================= stage 3: normal, K=256, m = rf*gvb =================
    {
        f32x16 acc[2];
        acc[0] = (f32x16)0.0f; acc[1] = (f32x16)0.0f;

        #pragma unroll
        for (int ks = 0; ks < 16; ++ks) {
            bf16x8 tf = ldtf(t_lds, row_l, ks, kg);
            #pragma unroll
            for (int n = 0; n < 2; ++n) {
                bf16x8 wf = ldw(w3s, ks, f * 2 + n, kg, l31);
                acc[n] = __builtin_amdgcn_mfma_f32_32x32x16_bf16(tf, wf, acc[n], 0, 0, 0);
            }
        }

        // epilogue: packed b32 stores, column-permuted within the f-quarter
        #pragma unroll
        for (int r = 0; r < 16; ++r) {
            const int lrow = (r & 3) + 8 * (r >> 2) + 4 * kg;
            const int gi = blk0 + lrow;
            if (gi < E) {
                float gbv = gvb_lds[lrow];
                float v0 = acc[0][r] * gbv;
                float v1 = acc[1][r] * gbv;
                *(unsigned*)(m + (size_t)gi * 256 + f * 64 + l31 * 2) = pack2(v0, v1);
            }
        }
    }
}

// ---------------- segment sum + feat gather: one wave per dst ----------------
// h[d] = sum_i ( m[i] + ga[i]*feat[src_i] ), all in the permuted column space:
// stored pos (q*64 + 4b + t), b=lane&15, maps to true col q*64 + {2b, 32+2b, 2b+1, 33+2b}
__global__ __launch_bounds__(256) void segsum_kernel(
    const int* __restrict__ start, const unsigned short* __restrict__ m,
    const float* __restrict__ ga, const int* __restrict__ esrc_s,
    const float* __restrict__ feat, unsigned short* __restrict__ h, int ND)
{
    int d = blockIdx.x * 4 + (threadIdx.x >> 6);
    if (d >= ND) return;
    int lane = threadIdx.x & 63;
    int q = lane >> 4;                 // feature quarter
    int b = lane & 15;
    int foff = q * 64 + 2 * b;         // true-col base for this lane
    int s0 = start[d], s1 = start[d + 1];
    float a0 = 0.f, a1 = 0.f, a2 = 0.f, a3 = 0.f;
    for (int i = s0; i < s1; ++i) {
        float gav = ga[i];
        const float* fp = feat + (size_t)esrc_s[i] * 256 + foff;
        float2 fa = *(const float2*)fp;          // true cols 2b, 2b+1
        float2 fb = *(const float2*)(fp + 32);   // true cols 32+2b, 33+2b
        ushort4 v = *(const ushort4*)(m + (size_t)i * 256 + lane * 4);
        a0 += bf2f(v.x) + fa.x * gav;
        a1 += bf2f(v.y) + fb.x * gav;
        a2 += bf2f(v.z) + fa.y * gav;
        a3 += bf2f(v.w) + fb.y * gav;
    }
    ushort4 o; o.x = f2bf(a0); o.y = f2bf(a1); o.z = f2bf(a2); o.w = f2bf(a3);
    *(ushort4*)(h + (size_t)d * 256 + lane * 4) = o;
}

// ---------------- g4: out = (h @ lin_w^T)*ci + b (perm baked into lws) ----------------
__global__ __launch_bounds__(256, 2) void g4_kernel(
    const unsigned short* __restrict__ Ab, const unsigned short* __restrict__ lws,
    float* __restrict__ outf, const float* __restrict__ ci,
    const float* __restrict__ bias, int M)
{
    const int lane = threadIdx.x & 63;
    const int wid  = threadIdx.x >> 6;
    const int l31  = lane & 31;
    const int kg   = lane >> 5;
    const int f    = wid & 1;                 // column half
    const int wbase = blockIdx.x * 128 + (wid >> 1) * 64;
    const int r0 = wbase + l31, r1 = wbase + 32 + l31;
    const int ar0 = (r0 < M) ? r0 : (M - 1);
    const int ar1 = (r1 < M) ? r1 : (M - 1);

    f32x16 acc[2][4];
    #pragma unroll
    for (int mi = 0; mi < 2; ++mi)
        #pragma unroll
        for (int n = 0; n < 4; ++n) acc[mi][n] = (f32x16)0.0f;

    #pragma unroll
    for (int ks = 0; ks < 16; ++ks) {
        const int kk = ks * 16 + kg * 8;
        bf16x8 a0 = *(const bf16x8*)(Ab + (size_t)ar0 * 256 + kk);
        bf16x8 a1 = *(const bf16x8*)(Ab + (size_t)ar1 * 256 + kk);
        #pragma unroll
        for (int n = 0; n < 4; ++n) {
            bf16x8 b = ldw(lws, ks, f * 4 + n, kg, l31);
            acc[0][n] = __builtin_amdgcn_mfma_f32_32x32x16_bf16(a0, b, acc[0][n], 0, 0, 0);
            acc[1][n] = __builtin_amdgcn_mfma_f32_32x32x16_bf16(a1, b, acc[1][n], 0, 0, 0);
        }
    }
    #pragma unroll
    for (int mi = 0; mi < 2; ++mi) {
        #pragma unroll
        for (int r = 0; r < 16; ++r) {
            const int gr = wbase + mi * 32 + (r & 3) + 8 * (r >> 2) + 4 * kg;
            if (gr >= M) continue;
            float civ = ci[gr];
            #pragma unroll
            for (int n = 0; n < 4; ++n) {
                int col = f * 128 + n * 32 + l31;
                outf[(size_t)gr * 256 + col] = acc[mi][n][r] * civ + bias[col];
            }
        }
    }
}

extern "C" void kernel_launch(void* const* d_in, const int* in_sizes, int n_in,
                              void* d_out, int out_size, void* d_ws, size_t ws_size,
                              hipStream_t stream) {
    const float* feat = (const float*)d_in[0];
    const float* cj   = (const float*)d_in[1];
    const float* ci   = (const float*)d_in[2];
    const int*   esrc = (const int*)d_in[3];
    const int*   edst = (const int*)d_in[4];
    const int*   rid  = (const int*)d_in[5];
    const float* remb = (const float*)d_in[6];
    const float* pw   = (const float*)d_in[7];
    const float* sw   = (const float*)d_in[8];
    const float* rw1  = (const float*)d_in[9];
    const float* rw2  = (const float*)d_in[10];
    const float* rw3  = (const float*)d_in[11];
    const float* lw   = (const float*)d_in[12];
    const float* lb   = (const float*)d_in[13];
    float* out = (float*)d_out;

    const int E  = in_sizes[3];   // 300000
    const int ND = in_sizes[2];   // 100000

    // workspace carve-up (~210 MB)
    char* ws = (char*)d_ws;
    float* ga = (float*)ws;                               // E f32
    unsigned short* m   = (unsigned short*)(ga + E);      // E*256 bf16 (permuted cols)
    unsigned short* h   = m + (size_t)E * 256;            // ND*256 bf16 (permuted cols)
    unsigned short* w1s = h + (size_t)ND * 256;           // 32768
    unsigned short* w2s = w1s + 32768;                    // 65536
    unsigned short* w3s = w2s + 65536;                    // 65536
    unsigned short* lws = w3s + 65536;                    // 65536
    int* cnt    = (int*)(lws + 65536);                    // ND
    int* start  = cnt + ND;                               // ND+1
    int* bsum   = start + ND + 1;                         // 128
    int* within = bsum + 128;                             // E
    int* rid_s  = within + E;                             // E
    int* esrc_s = rid_s + E;                              // E

    const int NB = (ND + 1023) / 1024;

    hipMemsetAsync(cnt, 0, (size_t)ND * sizeof(int), stream);
    prep_weights<<<256, 256, 0, stream>>>(rw1, rw2, rw3, lw, w1s, w2s, w3s, lws);

    // CSR build + direct sorted-edge emit
    hist_kernel<<<(E + 255) / 256, 256, 0, stream>>>(edst, cnt, within, E);
    scan_block<<<NB, 1024, 0, stream>>>(cnt, start, bsum, ND);
    scan_bsum<<<1, 64, 0, stream>>>(bsum, NB);
    add_offsets<<<NB, 1024, 0, stream>>>(start, bsum, ND, E);
    build_sorted<<<(E + 255) / 256, 256, 0, stream>>>(edst, within, start, rid, esrc,
                                                      rid_s, esrc_s, E);

    // fused g1+g2+g3 (4 waves, 32 edges/block, 16KB LDS, 5 blocks/CU)
    fused_edge<<<(E + 31) / 32, 256, 0, stream>>>(
        remb, rid_s, esrc_s, w1s, w2s, w3s, pw, sw, cj, ga, m, E);

    // segsum over contiguous sorted rows + feat[src]*ga gather
    segsum_kernel<<<(ND + 3) / 4, 256, 0, stream>>>(start, m, ga, esrc_s, feat, h, ND);

    // g4
    g4_kernel<<<(ND + 127) / 128, 256, 0, stream>>>(h, lws, out, ci, lb, ND);
}

// Round 11
// 418.900 us; speedup vs baseline: 1.2919x; 1.1084x over previous
//
#include <hip/hip_runtime.h>
#include <math.h>
#include <stdint.h>

// Fused pipeline (E=300000, ND=100000, FEAT=256, RDIM=128):
//   prep:   weights -> bf16 fragment-ordered tables (lws additionally k-permuted)
//   CSR:    hist, scan, scan_bsum, add_offsets, build_sorted (dst-sorted rid_s/esrc_s)
//   fused (256 thr = 4 waves, one per feature-quarter f; 32 edges/block;
//          LDS = t_rb 8KB (bf16 remb stage) + t_lds 16KB + gvb; ~24.7KB -> 6 blk/CU):
//     stage: block's 32 remb rows loaded COALESCED (thread-contiguous 32B) ->
//            cvt_pk -> t_rb bf16 (kills the 32-line/instr gather fanout of R10)
//     s1 (swapped mfma, K=128): A-frags via single ds_read_b128 from t_rb;
//         pa/ra dots from the same frags, ONLY f==0 wave; ga->global, gvb->LDS
//     s2 (swapped, K=256):      t2 = gelu(W2 @ t1)  (t_lds in-place)
//     s3 (normal, K=256):       m = (t2 @ W3^T)*gvb, col-PERMUTED packed b32:
//         stored[f*64 + l31*2 + n] = true col f*64 + n*32 + l31
//   segsum: h[d] = sum_i ( m[i] + ga[i]*feat[src_i] )  (permuted space)
//   g4:     out = (h @ lin_w^T)*ci + b   (perm inverted inside lws prep)
// Swizzles use row&15 (not &7): rows 16 apart no longer alias -> <=2-way (free).
// mfma_f32_32x32x16_bf16 layouts (HW-validated R2-R10):
//   A: row=lane&31, k=8*(lane>>5)+j ; B: col=lane&31, same k
//   D: col=lane&31, row=(reg&3)+8*(reg>>2)+4*(lane>>5)

typedef short bf16x8 __attribute__((ext_vector_type(8)));
typedef float f32x16 __attribute__((ext_vector_type(16)));

__device__ __forceinline__ float bf2f(unsigned short v) {
    union { unsigned int u; float f; } x; x.u = ((unsigned int)v) << 16; return x.f;
}
__device__ __forceinline__ unsigned short f2bf(float f) {
    union { float f; unsigned int u; } x; x.f = f;
    unsigned int u = x.u;
    return (unsigned short)((u + 0x7FFFu + ((u >> 16) & 1u)) >> 16);
}
// single-instruction packed f32x2 -> bf16x2 (RTNE), low16 = lo
__device__ __forceinline__ unsigned pack2(float lo, float hi) {
    unsigned r;
    asm("v_cvt_pk_bf16_f32 %0, %1, %2" : "=v"(r) : "v"(lo), "v"(hi));
    return r;
}
// tanh-approx GELU (~8 VALU ops)
__device__ __forceinline__ float gelu_fast(float x) {
    float y = x * (0.7978845608f + 0.0356774081f * x * x);
    float e = __builtin_amdgcn_exp2f(y * 2.8853900818f);   // e^(2y)
    float th = 1.0f - 2.0f * __builtin_amdgcn_rcpf(e + 1.0f);
    return 0.5f * x * (1.0f + th);
}
__device__ __forceinline__ float sigmoidf(float x) {
    return 1.0f / (1.0f + expf(-x));
}

// weights -> bf16 fragment-ordered tables; lws gets the m/h column perm baked in
__global__ __launch_bounds__(256) void prep_weights(
    const float* __restrict__ rw1, const float* __restrict__ rw2,
    const float* __restrict__ rw3, const float* __restrict__ lw,
    unsigned short* __restrict__ w1s, unsigned short* __restrict__ w2s,
    unsigned short* __restrict__ w3s, unsigned short* __restrict__ lws)
{
    int i = blockIdx.x * blockDim.x + threadIdx.x;
    int j   = i & 7;
    int l   = (i >> 3) & 31;
    int kgg = (i >> 8) & 1;
    int n2  = (i >> 9) & 7;
    int ks  = i >> 12;
    if (i < 32768) {   // K=128: ks 0..7
        w1s[i] = f2bf(rw1[(n2 * 32 + l) * 128 + ks * 16 + kgg * 8 + j]);
    }
    if (i < 65536) {   // K=256: ks 0..15
        int row = n2 * 32 + l, k = ks * 16 + kgg * 8 + j;
        w2s[i] = f2bf(rw2[(size_t)row * 256 + k]);
        w3s[i] = f2bf(rw3[(size_t)row * 256 + k]);
        // stored pos k holds true col: (k & ~63) + (k&1)*32 + ((k&63)>>1)
        int ok = (k & 192) | ((k & 1) << 5) | ((k & 63) >> 1);
        lws[i] = f2bf(lw[(size_t)row * 256 + ok]);
    }
}

// fragment load from pre-swizzled table (contiguous, coalesced)
__device__ __forceinline__ bf16x8 ldw(const unsigned short* __restrict__ W,
                                      int ks, int nglob, int kg, int l31) {
    return *(const bf16x8*)(W + (((((ks * 8 + nglob) * 2) + kg) * 32 + l31) << 3));
}

// ---------------- CSR build ----------------
__global__ __launch_bounds__(256) void hist_kernel(
    const int* __restrict__ edst, int* __restrict__ cnt,
    int* __restrict__ within, int E)
{
    int e = blockIdx.x * blockDim.x + threadIdx.x;
    if (e < E) within[e] = atomicAdd(&cnt[edst[e]], 1);
}

__global__ __launch_bounds__(1024) void scan_block(
    const int* __restrict__ cnt, int* __restrict__ start,
    int* __restrict__ bsum, int n)
{
    __shared__ int s[1024];
    int gid = blockIdx.x * 1024 + threadIdx.x;
    int v = (gid < n) ? cnt[gid] : 0;
    s[threadIdx.x] = v;
    __syncthreads();
    #pragma unroll
    for (int off = 1; off < 1024; off <<= 1) {
        int t = (threadIdx.x >= off) ? s[threadIdx.x - off] : 0;
        __syncthreads();
        if (threadIdx.x >= off) s[threadIdx.x] += t;
        __syncthreads();
    }
    if (gid < n) start[gid] = s[threadIdx.x] - v;   // exclusive
    if (threadIdx.x == 1023) bsum[blockIdx.x] = s[1023];
}

__global__ void scan_bsum(int* __restrict__ bsum, int nb) {
    if (threadIdx.x == 0 && blockIdx.x == 0) {
        int acc = 0;
        for (int i = 0; i < nb; ++i) { int v = bsum[i]; bsum[i] = acc; acc += v; }
    }
}

__global__ __launch_bounds__(1024) void add_offsets(
    int* __restrict__ start, const int* __restrict__ bsum, int n, int E)
{
    int gid = blockIdx.x * 1024 + threadIdx.x;
    if (gid < n) start[gid] += bsum[gid >> 10];
    if (gid == 0) start[n] = E;
}

// counting sort: directly emit dst-sorted rid/esrc (no eidx indirection)
__global__ __launch_bounds__(256) void build_sorted(
    const int* __restrict__ edst, const int* __restrict__ within,
    const int* __restrict__ start, const int* __restrict__ rid,
    const int* __restrict__ esrc, int* __restrict__ rid_s,
    int* __restrict__ esrc_s, int E)
{
    int e = blockIdx.x * blockDim.x + threadIdx.x;
    if (e < E) {
        int pos = start[edst[e]] + within[e];
        rid_s[pos]  = rid[e];
        esrc_s[pos] = esrc[e];
    }
}

// ---------------- LDS helpers (16B-slot XOR swizzle, row&15) ----------------
// t_lds: 32 rows x 512B (32 slots); t_rb: 32 rows x 256B (16 slots)
__device__ __forceinline__ bf16x8 ldtf(const unsigned short* t_lds, int row, int ks, int kg) {
    int slot = (ks * 2 + kg) ^ (row & 15);
    return *(const bf16x8*)((const char*)t_lds + row * 512 + slot * 16);
}
__device__ __forceinline__ void sttf(unsigned short* t_lds, int row, int nn, int p, int kg, uint2 w) {
    int slot = (nn * 4 + p) ^ (row & 15);
    *(uint2*)((char*)t_lds + row * 512 + slot * 16 + kg * 8) = w;
}
__device__ __forceinline__ bf16x8 ldrb(const unsigned short* t_rb, int row, int ks, int kg) {
    int slot = (ks * 2 + kg) ^ (row & 15);
    return *(const bf16x8*)((const char*)t_rb + row * 256 + slot * 16);
}

// ---------------- fused g1+g2+g3 ----------------
__global__ __launch_bounds__(256, 5) void fused_edge(
    const float* __restrict__ remb, const int* __restrict__ rid_s,
    const int* __restrict__ esrc_s,
    const unsigned short* __restrict__ w1s, const unsigned short* __restrict__ w2s,
    const unsigned short* __restrict__ w3s,
    const float* __restrict__ pw, const float* __restrict__ sw,
    const float* __restrict__ cj, float* __restrict__ ga,
    unsigned short* __restrict__ m, int E)
{
    __shared__ __align__(16) unsigned short t_lds[32 * 256];   // 16 KB
    __shared__ __align__(16) unsigned short t_rb[32 * 128];    // 8 KB bf16 remb
    __shared__ float gvb_lds[32];

    const int lane = threadIdx.x & 63;
    const int f    = threadIdx.x >> 6;       // wave = feature quarter 0..3
    const int l31  = lane & 31;
    const int kg   = lane >> 5;              // 0..1
    const int blk0 = blockIdx.x * 32;
    const int i    = blk0 + l31;             // lane's edge
    const int ic   = (i < E) ? i : (E - 1);
    const int row_l = l31;                   // local LDS row

    // ---- stage remb rows coalesced -> t_rb (bf16) ----
    {
        const int t = threadIdx.x;
        #pragma unroll
        for (int p = 0; p < 2; ++p) {
            int sIdx = p * 256 + t;              // 0..511
            int row  = sIdx >> 4;                // 0..31
            int c16  = sIdx & 15;                // 16B slot within row
            int gr   = blk0 + row;
            int rr   = rid_s[(gr < E) ? gr : (E - 1)];
            const float* sp = remb + (size_t)rr * 128 + c16 * 8;
            float4 a = *(const float4*)sp;
            float4 b = *(const float4*)(sp + 4);
            uint4 w;
            w.x = pack2(a.x, a.y); w.y = pack2(a.z, a.w);
            w.z = pack2(b.x, b.y); w.w = pack2(b.z, b.w);
            int slot = c16 ^ (row & 15);
            *(uint4*)((char*)t_rb + row * 256 + slot * 16) = w;
        }
    }
    __syncthreads();

    // ================= stage 1: swapped, K=128 (+ dots in f==0) =================
    {
        f32x16 acc[2];
        acc[0] = (f32x16)0.0f; acc[1] = (f32x16)0.0f;
        float pd = 0.f, rd = 0.f;

        #pragma unroll
        for (int ks = 0; ks < 8; ++ks) {
            bf16x8 af = ldrb(t_rb, row_l, ks, kg);
            if (f == 0) {   // wave-uniform: only f==0 pays for the dots
                const int kk = ks * 16 + kg * 8;
                float4 p0 = *(const float4*)(pw + kk), p1 = *(const float4*)(pw + kk + 4);
                float4 s0 = *(const float4*)(sw + kk), s1v = *(const float4*)(sw + kk + 4);
                float v0 = bf2f((unsigned short)af[0]), v1 = bf2f((unsigned short)af[1]);
                float v2 = bf2f((unsigned short)af[2]), v3 = bf2f((unsigned short)af[3]);
                float v4 = bf2f((unsigned short)af[4]), v5 = bf2f((unsigned short)af[5]);
                float v6 = bf2f((unsigned short)af[6]), v7 = bf2f((unsigned short)af[7]);
                pd += v0*p0.x + v1*p0.y + v2*p0.z + v3*p0.w
                    + v4*p1.x + v5*p1.y + v6*p1.z + v7*p1.w;
                rd += v0*s0.x + v1*s0.y + v2*s0.z + v3*s0.w
                    + v4*s1v.x + v5*s1v.y + v6*s1v.z + v7*s1v.w;
            }
            #pragma unroll
            for (int n = 0; n < 2; ++n) {
                bf16x8 wf = ldw(w1s, ks, f * 2 + n, kg, l31);
                acc[n] = __builtin_amdgcn_mfma_f32_32x32x16_bf16(wf, af, acc[n], 0, 0, 0);
            }
        }

        if (f == 0) {
            pd += __shfl_xor(pd, 32);
            rd += __shfl_xor(rd, 32);
            if (lane < 32) {
                float cjv = cj[esrc_s[ic]];
                if (i < E) ga[i] = sigmoidf(pd) * cjv;   // segsum applies feat term
                gvb_lds[l31] = sigmoidf(rd) * cjv;
            }
        }

        #pragma unroll
        for (int n = 0; n < 2; ++n)
            #pragma unroll
            for (int p = 0; p < 4; ++p) {
                uint2 w;
                w.x = pack2(gelu_fast(acc[n][4*p + 0]), gelu_fast(acc[n][4*p + 1]));
                w.y = pack2(gelu_fast(acc[n][4*p + 2]), gelu_fast(acc[n][4*p + 3]));
                sttf(t_lds, row_l, f * 2 + n, p, kg, w);
            }
    }
    __syncthreads();

    // ================= stage 2: swapped, K=256, LDS in-place =================
    {
        f32x16 acc[2];
        acc[0] = (f32x16)0.0f; acc[1] = (f32x16)0.0f;

        #pragma unroll
        for (int ks = 0; ks < 16; ++ks) {
            bf16x8 tf = ldtf(t_lds, row_l, ks, kg);
            #pragma unroll
            for (int n = 0; n < 2; ++n) {
                bf16x8 wf = ldw(w2s, ks, f * 2 + n, kg, l31);
                acc[n] = __builtin_amdgcn_mfma_f32_32x32x16_bf16(wf, tf, acc[n], 0, 0, 0);
            }
        }
        __syncthreads();   // all reads of t1 done before overwrite
        #pragma unroll
        for (int n = 0; n < 2; ++n)
            #pragma unroll
            for (int p = 0; p < 4; ++p) {
                uint2 w;
                w.x = pack2(gelu_fast(acc[n][4*p + 0]), gelu_fast(acc[n][4*p + 1]));
                w.y = pack2(gelu_fast(acc[n][4*p + 2]), gelu_fast(acc[n][4*p + 3]));
                sttf(t_lds, row_l, f * 2 + n, p, kg, w);
            }
    }
    __syncthreads();

    // ================= stage 3: normal, K=256, m = rf*gvb =================
    {
        f32x16 acc[2];
        acc[0] = (f32x16)0.0f; acc[1] = (f32x16)0.0f;

        #pragma unroll
        for (int ks = 0; ks < 16; ++ks) {
            bf16x8 tf = ldtf(t_lds, row_l, ks, kg);
            #pragma unroll
            for (int n = 0; n < 2; ++n) {
                bf16x8 wf = ldw(w3s, ks, f * 2 + n, kg, l31);
                acc[n] = __builtin_amdgcn_mfma_f32_32x32x16_bf16(tf, wf, acc[n], 0, 0, 0);
            }
        }

        // epilogue: packed b32 stores, column-permuted within the f-quarter
        #pragma unroll
        for (int r = 0; r < 16; ++r) {
            const int lrow = (r & 3) + 8 * (r >> 2) + 4 * kg;
            const int gi = blk0 + lrow;
            if (gi < E) {
                float gbv = gvb_lds[lrow];
                float v0 = acc[0][r] * gbv;
                float v1 = acc[1][r] * gbv;
                *(unsigned*)(m + (size_t)gi * 256 + f * 64 + l31 * 2) = pack2(v0, v1);
            }
        }
    }
}

// ---------------- segment sum + feat gather: one wave per dst ----------------
// h[d] = sum_i ( m[i] + ga[i]*feat[src_i] ), all in the permuted column space:
// stored pos (q*64 + 4b + t), b=lane&15, maps to true col q*64 + {2b, 32+2b, 2b+1, 33+2b}
__global__ __launch_bounds__(256) void segsum_kernel(
    const int* __restrict__ start, const unsigned short* __restrict__ m,
    const float* __restrict__ ga, const int* __restrict__ esrc_s,
    const float* __restrict__ feat, unsigned short* __restrict__ h, int ND)
{
    int d = blockIdx.x * 4 + (threadIdx.x >> 6);
    if (d >= ND) return;
    int lane = threadIdx.x & 63;
    int q = lane >> 4;                 // feature quarter
    int b = lane & 15;
    int foff = q * 64 + 2 * b;         // true-col base for this lane
    int s0 = start[d], s1 = start[d + 1];
    float a0 = 0.f, a1 = 0.f, a2 = 0.f, a3 = 0.f;
    for (int i = s0; i < s1; ++i) {
        float gav = ga[i];
        const float* fp = feat + (size_t)esrc_s[i] * 256 + foff;
        float2 fa = *(const float2*)fp;          // true cols 2b, 2b+1
        float2 fb = *(const float2*)(fp + 32);   // true cols 32+2b, 33+2b
        ushort4 v = *(const ushort4*)(m + (size_t)i * 256 + lane * 4);
        a0 += bf2f(v.x) + fa.x * gav;
        a1 += bf2f(v.y) + fb.x * gav;
        a2 += bf2f(v.z) + fa.y * gav;
        a3 += bf2f(v.w) + fb.y * gav;
    }
    ushort4 o; o.x = f2bf(a0); o.y = f2bf(a1); o.z = f2bf(a2); o.w = f2bf(a3);
    *(ushort4*)(h + (size_t)d * 256 + lane * 4) = o;
}

// ---------------- g4: out = (h @ lin_w^T)*ci + b (perm baked into lws) ----------------
__global__ __launch_bounds__(256, 2) void g4_kernel(
    const unsigned short* __restrict__ Ab, const unsigned short* __restrict__ lws,
    float* __restrict__ outf, const float* __restrict__ ci,
    const float* __restrict__ bias, int M)
{
    const int lane = threadIdx.x & 63;
    const int wid  = threadIdx.x >> 6;
    const int l31  = lane & 31;
    const int kg   = lane >> 5;
    const int f    = wid & 1;                 // column half
    const int wbase = blockIdx.x * 128 + (wid >> 1) * 64;
    const int r0 = wbase + l31, r1 = wbase + 32 + l31;
    const int ar0 = (r0 < M) ? r0 : (M - 1);
    const int ar1 = (r1 < M) ? r1 : (M - 1);

    f32x16 acc[2][4];
    #pragma unroll
    for (int mi = 0; mi < 2; ++mi)
        #pragma unroll
        for (int n = 0; n < 4; ++n) acc[mi][n] = (f32x16)0.0f;

    #pragma unroll
    for (int ks = 0; ks < 16; ++ks) {
        const int kk = ks * 16 + kg * 8;
        bf16x8 a0 = *(const bf16x8*)(Ab + (size_t)ar0 * 256 + kk);
        bf16x8 a1 = *(const bf16x8*)(Ab + (size_t)ar1 * 256 + kk);
        #pragma unroll
        for (int n = 0; n < 4; ++n) {
            bf16x8 b = ldw(lws, ks, f * 4 + n, kg, l31);
            acc[0][n] = __builtin_amdgcn_mfma_f32_32x32x16_bf16(a0, b, acc[0][n], 0, 0, 0);
            acc[1][n] = __builtin_amdgcn_mfma_f32_32x32x16_bf16(a1, b, acc[1][n], 0, 0, 0);
        }
    }
    #pragma unroll
    for (int mi = 0; mi < 2; ++mi) {
        #pragma unroll
        for (int r = 0; r < 16; ++r) {
            const int gr = wbase + mi * 32 + (r & 3) + 8 * (r >> 2) + 4 * kg;
            if (gr >= M) continue;
            float civ = ci[gr];
            #pragma unroll
            for (int n = 0; n < 4; ++n) {
                int col = f * 128 + n * 32 + l31;
                outf[(size_t)gr * 256 + col] = acc[mi][n][r] * civ + bias[col];
            }
        }
    }
}

extern "C" void kernel_launch(void* const* d_in, const int* in_sizes, int n_in,
                              void* d_out, int out_size, void* d_ws, size_t ws_size,
                              hipStream_t stream) {
    const float* feat = (const float*)d_in[0];
    const float* cj   = (const float*)d_in[1];
    const float* ci   = (const float*)d_in[2];
    const int*   esrc = (const int*)d_in[3];
    const int*   edst = (const int*)d_in[4];
    const int*   rid  = (const int*)d_in[5];
    const float* remb = (const float*)d_in[6];
    const float* pw   = (const float*)d_in[7];
    const float* sw   = (const float*)d_in[8];
    const float* rw1  = (const float*)d_in[9];
    const float* rw2  = (const float*)d_in[10];
    const float* rw3  = (const float*)d_in[11];
    const float* lw   = (const float*)d_in[12];
    const float* lb   = (const float*)d_in[13];
    float* out = (float*)d_out;

    const int E  = in_sizes[3];   // 300000
    const int ND = in_sizes[2];   // 100000

    // workspace carve-up (~210 MB)
    char* ws = (char*)d_ws;
    float* ga = (float*)ws;                               // E f32
    unsigned short* m   = (unsigned short*)(ga + E);      // E*256 bf16 (permuted cols)
    unsigned short* h   = m + (size_t)E * 256;            // ND*256 bf16 (permuted cols)
    unsigned short* w1s = h + (size_t)ND * 256;           // 32768
    unsigned short* w2s = w1s + 32768;                    // 65536
    unsigned short* w3s = w2s + 65536;                    // 65536
    unsigned short* lws = w3s + 65536;                    // 65536
    int* cnt    = (int*)(lws + 65536);                    // ND
    int* start  = cnt + ND;                               // ND+1
    int* bsum   = start + ND + 1;                         // 128
    int* within = bsum + 128;                             // E
    int* rid_s  = within + E;                             // E
    int* esrc_s = rid_s + E;                              // E

    const int NB = (ND + 1023) / 1024;

    hipMemsetAsync(cnt, 0, (size_t)ND * sizeof(int), stream);
    prep_weights<<<256, 256, 0, stream>>>(rw1, rw2, rw3, lw, w1s, w2s, w3s, lws);

    // CSR build + direct sorted-edge emit
    hist_kernel<<<(E + 255) / 256, 256, 0, stream>>>(edst, cnt, within, E);
    scan_block<<<NB, 1024, 0, stream>>>(cnt, start, bsum, ND);
    scan_bsum<<<1, 64, 0, stream>>>(bsum, NB);
    add_offsets<<<NB, 1024, 0, stream>>>(start, bsum, ND, E);
    build_sorted<<<(E + 255) / 256, 256, 0, stream>>>(edst, within, start, rid, esrc,
                                                      rid_s, esrc_s, E);

    // fused g1+g2+g3 (4 waves, 32 edges/block, coalesced remb staging)
    fused_edge<<<(E + 31) / 32, 256, 0, stream>>>(
        remb, rid_s, esrc_s, w1s, w2s, w3s, pw, sw, cj, ga, m, E);

    // segsum over contiguous sorted rows + feat[src]*ga gather
    segsum_kernel<<<(ND + 3) / 4, 256, 0, stream>>>(start, m, ga, esrc_s, feat, h, ND);

    // g4
    g4_kernel<<<(ND + 127) / 128, 256, 0, stream>>>(h, lws, out, ci, lb, ND);
}